// Round 2
// baseline (104.071 us; speedup 1.0000x reference)
//
#include <hip/hip_runtime.h>
#include <math.h>

typedef float f32x2 __attribute__((ext_vector_type(2)));

#define N_OBJ 16
#define P 4096                     // P1 == P2
#define BLOCK 256
#define R 8                        // rows per thread
#define ROWS_PER_BLOCK (BLOCK * R) // 2048
#define ROWBLOCKS (P / ROWS_PER_BLOCK) // 2
#define CQ 16                      // chunks along the min-dimension
#define QCHUNK (P / CQ)            // 256
#define JP (QCHUNK / 2)            // 128 j-pairs per chunk
#define EPSF 1e-12f

// ---------------------------------------------------------------------------
// Kernel 1: init min-buffers to +INF, zero the output scalar, compute masks.
// Blocks [0,128): grid-stride fill of 2*N_OBJ*P ints with 0x7F800000 (+inf).
// Blocks [128,144): block n-128 sums set2[n] (8192 floats) -> mask[n].
// ---------------------------------------------------------------------------
__global__ __launch_bounds__(BLOCK) void k_init(const float* __restrict__ s2,
                                                int* __restrict__ minbuf,
                                                float* __restrict__ maskbuf,
                                                float* __restrict__ out) {
    int bid = blockIdx.x;
    int tid = threadIdx.x;
    if (bid < 128) {
        const int total = 2 * N_OBJ * P; // 131072
        for (int i = bid * BLOCK + tid; i < total; i += 128 * BLOCK)
            minbuf[i] = 0x7F800000; // +inf as float
        if (bid == 0 && tid == 0) out[0] = 0.0f;
    } else {
        int n = bid - 128;
        __shared__ float red[BLOCK];
        float s = 0.0f;
        for (int i = tid; i < 2 * P; i += BLOCK)
            s += s2[n * 2 * P + i];
        red[tid] = s;
        __syncthreads();
        for (int off = BLOCK / 2; off > 0; off >>= 1) {
            if (tid < off) red[tid] += red[tid + off];
            __syncthreads();
        }
        if (tid == 0) maskbuf[n] = (red[0] >= 0.0f) ? 1.0f : 0.0f;
    }
}

// ---------------------------------------------------------------------------
// Kernel 2: pairwise min passes, packed-fp32 inner loop.
// pass 0: rows = set1 points (min over set2)  -> rowmin
// pass 1: rows = set2 points (min over set1)  -> colmin
// Per-pair: s = x2 + y2 - 2(x0*y0 + x1*y1).  Hoist x2 out of the min:
//   m = min_j fma(-2*x0, y0_j, fma(-2*x1, y1_j, y2_j)); final = m + x2.
// Inner loop processes j-PAIRS: both FMAs become v_pk_fma_f32 (row coeffs are
// pre-splatted f32x2), and min(min(d.lo,d.hi), m) folds to v_min3_f32.
// ~1.75 VALU insts/pair vs 3.0 scalar.
// Clamp to EPS (positive) then int-punned atomicMin (valid for floats >= 0).
// ---------------------------------------------------------------------------
__global__ __launch_bounds__(BLOCK) void k_main(const float* __restrict__ s1,
                                                const float* __restrict__ s2,
                                                const float* __restrict__ maskbuf,
                                                int* __restrict__ rowmin,
                                                int* __restrict__ colmin) {
    const int per_pass = N_OBJ * ROWBLOCKS * CQ; // 512
    int bid  = blockIdx.x;
    int pass = bid / per_pass;
    int idx  = bid % per_pass;
    int n    = idx / (ROWBLOCKS * CQ);
    int rem  = idx % (ROWBLOCKS * CQ);
    int rb   = rem / CQ;
    int cq   = rem % CQ;

    if (maskbuf[n] == 0.0f) return; // masked object: contributes 0, skip all work

    const float* T = (pass == 0) ? s1 : s2; // "row" points (one per accumulator)
    const float* S = (pass == 0) ? s2 : s1; // points we minimize over (staged)
    int* outmin    = (pass == 0) ? rowmin : colmin;

    // LDS entry per j-pair: (y0_a, y0_b, y1_a, y1_b) so the two register pairs
    // of a b128 read are directly the packed y0 and y1 operands.
    __shared__ float4 lds[JP];
    int tid = threadIdx.x;

    if (tid < JP) {
        int q = cq * QCHUNK + 2 * tid; // even
        float4 v = ((const float4*)S)[(n * P + q) >> 1]; // (y0a,y1a,y0b,y1b)
        lds[tid] = make_float4(v.x, v.z, v.y, v.w);      // swizzle to (y0a,y0b,y1a,y1b)
    }

    // Load this thread's R rows; splat coefficients into packed pairs once.
    f32x2 a0s[R], a1s[R];
    float c[R], m[R];
    int rbase = rb * ROWS_PER_BLOCK;
#pragma unroll
    for (int k = 0; k < R; k++) {
        int r = rbase + k * BLOCK + tid;
        float2 x = ((const float2*)T)[n * P + r];
        float a0 = -2.0f * x.x, a1 = -2.0f * x.y;
        a0s[k] = (f32x2){a0, a0};
        a1s[k] = (f32x2){a1, a1};
        c[k]   = fmaf(x.x, x.x, x.y * x.y);
        m[k]   = INFINITY;
    }
    __syncthreads();

#pragma unroll 4
    for (int jp = 0; jp < JP; jp++) {
        float4 v = lds[jp];            // broadcast read, conflict-free
        f32x2 y0 = {v.x, v.y};
        f32x2 y1 = {v.z, v.w};
        f32x2 y2 = y0 * y0 + y1 * y1;  // pk_mul + pk_fma (contract=fast)
#pragma unroll
        for (int k = 0; k < R; k++) {
            f32x2 t = a1s[k] * y1 + y2;   // v_pk_fma_f32
            f32x2 d = a0s[k] * y0 + t;    // v_pk_fma_f32
            m[k] = fminf(fminf(d.x, d.y), m[k]); // v_min3_f32
        }
    }

#pragma unroll
    for (int k = 0; k < R; k++) {
        int r = rbase + k * BLOCK + tid;
        float val = fmaxf(m[k] + c[k], EPSF); // clip(., EPS): positive => int order ok
        atomicMin(&outmin[n * P + r], __float_as_int(val));
    }
}

// ---------------------------------------------------------------------------
// Kernel 3: per-object finalize. Block n sums sqrt(min) over both directions,
// cost_n = 0.5*(sum1 + sum2)/P ; atomicAdd(out, cost_n/N).
// ---------------------------------------------------------------------------
__global__ __launch_bounds__(BLOCK) void k_obj(const int* __restrict__ rowmin,
                                               const int* __restrict__ colmin,
                                               const float* __restrict__ maskbuf,
                                               float* __restrict__ out) {
    int n = blockIdx.x;
    if (maskbuf[n] == 0.0f) return;
    int tid = threadIdx.x;
    __shared__ float red[BLOCK];
    float s = 0.0f;
    for (int i = tid; i < P; i += BLOCK)
        s += sqrtf(__int_as_float(rowmin[n * P + i]));
    for (int i = tid; i < P; i += BLOCK)
        s += sqrtf(__int_as_float(colmin[n * P + i]));
    red[tid] = s;
    __syncthreads();
    for (int off = BLOCK / 2; off > 0; off >>= 1) {
        if (tid < off) red[tid] += red[tid + off];
        __syncthreads();
    }
    if (tid == 0) {
        float cost = 0.5f * (red[0] / (float)P); // 0.5*(d1+d2), P1==P2
        atomicAdd(out, cost * (1.0f / (float)N_OBJ));
    }
}

extern "C" void kernel_launch(void* const* d_in, const int* in_sizes, int n_in,
                              void* d_out, int out_size, void* d_ws, size_t ws_size,
                              hipStream_t stream) {
    const float* s1 = (const float*)d_in[0]; // [16,4096,2] fp32
    const float* s2 = (const float*)d_in[1]; // [16,4096,2] fp32
    float* out = (float*)d_out;              // scalar fp32

    int*   rowmin  = (int*)d_ws;                       // 65536 ints
    int*   colmin  = rowmin + N_OBJ * P;               // 65536 ints
    float* maskbuf = (float*)(colmin + N_OBJ * P);     // 16 floats

    k_init<<<144, BLOCK, 0, stream>>>(s2, rowmin, maskbuf, out);
    k_main<<<2 * N_OBJ * ROWBLOCKS * CQ, BLOCK, 0, stream>>>(s1, s2, maskbuf,
                                                             rowmin, colmin);
    k_obj<<<N_OBJ, BLOCK, 0, stream>>>(rowmin, colmin, maskbuf, out);
}